// Round 6
// baseline (742.344 us; speedup 1.0000x reference)
//
#include <hip/hip_runtime.h>
#include <cstdint>
#include <cstddef>

// Problem constants
#define NB 512
#define NR 1152
#define NC 8
#define NJ 10
#define NO 16
#define NJO 160   // NJ*NO

// Tiling: block = (36 r x 32 b), 18 slices of 2 r. Grid (32, 16) = 512 blocks.
#define RC 36
#define BT 32
#define NSL 18

typedef unsigned int uint32;

__device__ __forceinline__ float dot8(const float4& a, const float4& b,
                                      const float* x) {
    return a.x * x[0] + a.y * x[1] + a.z * x[2] + a.w * x[3] +
           b.x * x[4] + b.y * x[5] + b.z * x[6] + b.w * x[7];
}

// ============================================================================
// Fused routing pass. u_hat is NEVER stored anywhere (recomputed from W,x in
// both phases; FMA is cheap, memory/LDS-pipe is not).
// Per slice (2 r):
//  stage: Ws[rr][jo][12-stride] (broadcast-friendly), xs[rr][c][36-stride]
//  B1 (skip if UNIFORM): thread (rr, b, o-quad q): b_ij = sum_o u[jo]*v[jo]
//     with u rebuilt inline from W,x; v in 40 regs (loaded once per pass from
//     fp32 vacc); quad shuffle combine; softmax -> cs[rr][b][j].
//  S : thread (col-run of 5, b-quad): acc[5][2][4] in regs accumulated over
//     all 18 slices; W 16 floats in regs per col (8-lane LDS broadcast);
//     x 32 floats in regs (conflict-free b128); jo-pair (2p,2p+1) shares one
//     j -> single c per col. End: 40 global atomicAdds.
// ============================================================================
template <bool UNIFORM>
__global__ __launch_bounds__(256, 2) void fused_pass(const float* __restrict__ x,
                                                     const float* __restrict__ W,
                                                     const float* __restrict__ vacc,
                                                     float* __restrict__ s) {
    const int rc0 = blockIdx.x * RC;
    const int b0  = blockIdx.y * BT;
    const int t   = threadIdx.x;

    __shared__ float Ws[2][NJO][12];  // rows stride 12 floats (48B, b128-OK)
    __shared__ float xs[2][NC][36];   // c-major, stride 36 (144B, b128-OK)
    __shared__ float cs[2][BT][12];   // softmax coeffs

    // ---- B1 identity ----
    const int q   = t & 3;            // o-quad
    const int ib  = (t >> 2) & 31;    // b
    const int irr = t >> 7;           // rr
    // ---- S identity ----
    const int bq   = t & 7;           // b-quad
    const int run  = t >> 3;          // 0..31
    const int col0 = run * 5;         // 0..155 (never crosses rr boundary: 80%5==0)
    const int srr  = (col0 >= 80) ? 1 : 0;
    const int p0   = col0 - 80 * srr; // jo-pair index 0..75

    // v in registers: v[j][m] = vacc[b0+ib][16j + 4q + m], loaded once per pass
    float vj[NJ][4];
    if (!UNIFORM) {
        const float4* vp = (const float4*)(vacc + (size_t)(b0 + ib) * NJO);
#pragma unroll
        for (int j = 0; j < NJ; ++j) {
            float4 vv = vp[j * 4 + q];
            vj[j][0] = vv.x; vj[j][1] = vv.y; vj[j][2] = vv.z; vj[j][3] = vv.w;
        }
    }

    float acc[5][2][4];
#pragma unroll
    for (int m = 0; m < 5; ++m)
#pragma unroll
        for (int i = 0; i < 2; ++i)
#pragma unroll
            for (int bb = 0; bb < 4; ++bb) acc[m][i][bb] = 0.0f;

#pragma unroll 1
    for (int sl = 0; sl < NSL; ++sl) {
        const int rbase = rc0 + sl * 2;

        __syncthreads();  // prev slice's S done reading Ws/xs/cs

        // stage Ws: 320 rows of 8 floats (row = rr*160 + jo)
        for (int row = t; row < 320; row += 256) {
            int rr = (row >= NJO) ? 1 : 0;
            int jo = row - NJO * rr;
            const float4* wp = (const float4*)&W[(size_t)(rbase + rr) * (NJO * NC) + jo * NC];
            float4 wa = wp[0], wb = wp[1];
            float* dst = &Ws[rr][jo][0];
            *(float4*)dst = wa;
            *(float4*)(dst + 4) = wb;
        }
        // stage xs: 512 floats, i -> (rr = i>>8, b = (i>>3)&31, c = i&7)
        for (int i = t; i < 512; i += 256) {
            int rr = i >> 8, b = (i >> 3) & 31, c = i & 7;
            xs[rr][c][b] = x[(size_t)(b0 + b) * (NR * NC) + (size_t)(rbase + rr) * NC + c];
        }
        __syncthreads();

        // ---- Phase B1 ----
        if (!UNIFORM) {
            float xr[8];
#pragma unroll
            for (int c = 0; c < 8; ++c) xr[c] = xs[irr][c][ib];

            float pj[NJ];
#pragma unroll
            for (int j = 0; j < NJ; ++j) {
                float a = 0.0f;
#pragma unroll
                for (int m = 0; m < 4; ++m) {
                    const float* wrow = &Ws[irr][16 * j + 4 * q + m][0];
                    float4 wa = *(const float4*)wrow;
                    float4 wb = *(const float4*)(wrow + 4);
                    float u = dot8(wa, wb, xr);
                    a += u * vj[j][m];
                }
                pj[j] = a;
            }
            // combine over the 4 q-lanes (quad xor -> DPP, not DS pipe)
            float ej[NJ];
            float sum = 0.0f;
#pragma unroll
            for (int j = 0; j < NJ; ++j) {
                float v1 = pj[j] + __shfl_xor(pj[j], 1);
                float bj = v1 + __shfl_xor(v1, 2);
                float e = __expf(bj);  // |bj| <~ 45, safe in fp32
                ej[j] = e;
                sum += e;
            }
            float inv = 1.0f / sum;
            if (q < 2) {
#pragma unroll
                for (int k = 0; k < 5; ++k) cs[irr][ib][5 * q + k] = ej[5 * q + k] * inv;
            }
            __syncthreads();
        }

        // ---- Phase S ----
        {
            float xr[4][8];
#pragma unroll
            for (int c = 0; c < 8; ++c) {
                float4 xv = *(const float4*)&xs[srr][c][4 * bq];
                xr[0][c] = xv.x; xr[1][c] = xv.y; xr[2][c] = xv.z; xr[3][c] = xv.w;
            }
#pragma unroll
            for (int m = 0; m < 5; ++m) {
                int p = p0 + m;
                int j = p >> 3;  // jo-pair (2p, 2p+1) shares this j
                const float* w0 = &Ws[srr][2 * p][0];
                const float* w1 = &Ws[srr][2 * p + 1][0];
                float4 w0a = *(const float4*)w0, w0b = *(const float4*)(w0 + 4);
                float4 w1a = *(const float4*)w1, w1b = *(const float4*)(w1 + 4);
#pragma unroll
                for (int bb = 0; bb < 4; ++bb) {
                    float c = UNIFORM ? 0.1f : cs[srr][4 * bq + bb][j];
                    float u0 = dot8(w0a, w0b, xr[bb]);
                    float u1 = dot8(w1a, w1b, xr[bb]);
                    acc[m][0][bb] += c * u0;
                    acc[m][1][bb] += c * u1;
                }
            }
        }
    }

    // global combine (32 r-chunk blocks x 2 rr-threads add per address)
#pragma unroll
    for (int m = 0; m < 5; ++m) {
        int p = p0 + m;
#pragma unroll
        for (int bb = 0; bb < 4; ++bb) {
            float* sp = &s[(size_t)(b0 + 4 * bq + bb) * NJO + 2 * p];
            atomicAdd(&sp[0], acc[m][0][bb]);
            atomicAdd(&sp[1], acc[m][1][bb]);
        }
    }
}

// ============================================================================
// Squash: per (b,j): sq = ||s_j||^2 (16-lane shfl), v = (sq/(1+sq))*s*rsqrt(..)
// MODE 0: vacc += v (fp32 running v-sum, read by next pass's B1).
// MODE 1: write v to out.
// ============================================================================
template <int MODE>
__global__ __launch_bounds__(256) void squash_kernel(const float* __restrict__ s,
                                                     float* __restrict__ vacc,
                                                     float* __restrict__ outp) {
    const int idx = blockIdx.x * 256 + threadIdx.x;  // < 81920; idx%16 = o
    float val = s[idx];
    float sq = val * val;
#pragma unroll
    for (int off = 1; off < 16; off <<= 1) sq += __shfl_xor(sq, off, 16);
    float scale = (sq / (1.0f + sq)) * rsqrtf(sq + 1e-8f);
    float v = val * scale;
    if (MODE == 1) outp[idx] = v;
    else           vacc[idx] += v;
}

// ============================================================================
extern "C" void kernel_launch(void* const* d_in, const int* in_sizes, int n_in,
                              void* d_out, int out_size, void* d_ws, size_t ws_size,
                              hipStream_t stream) {
    (void)in_sizes; (void)n_in; (void)out_size; (void)ws_size;

    const float* x = (const float*)d_in[0];  // [B,R,C]
    const float* W = (const float*)d_in[1];  // [R,J,O,C]
    float* out = (float*)d_out;              // [B,J,O,1] fp32

    char* ws = (char*)d_ws;
    float* s0   = (float*)ws;            // [B,160]
    float* s1   = s0 + NB * NJO;
    float* s2   = s1 + NB * NJO;
    float* vacc = s2 + NB * NJO;         // [B,160] fp32 running v-sum

    // zero s0,s1,s2,vacc (contiguous)
    hipMemsetAsync(s0, 0, (size_t)4 * NB * NJO * sizeof(float), stream);

    const dim3 fgrid(NR / RC, NB / BT);  // (32, 16) = 512 blocks
    const int  sgrid = (NB * NJO) / 256; // 320

    // iter 0: c uniform (=1/10) -> s0 ; v0 -> vacc
    fused_pass<true><<<fgrid, 256, 0, stream>>>(x, W, vacc, s0);
    squash_kernel<0><<<sgrid, 256, 0, stream>>>(s0, vacc, nullptr);

    // iter 1: b1 = u.v0 -> s1 ; vacc = v0+v1
    fused_pass<false><<<fgrid, 256, 0, stream>>>(x, W, vacc, s1);
    squash_kernel<0><<<sgrid, 256, 0, stream>>>(s1, vacc, nullptr);

    // iter 2: b2 = u.(v0+v1) -> s2 -> v2 = output
    fused_pass<false><<<fgrid, 256, 0, stream>>>(x, W, vacc, s2);
    squash_kernel<1><<<sgrid, 256, 0, stream>>>(s2, nullptr, out);
}

// Round 7
// 502.578 us; speedup vs baseline: 1.4771x; 1.4771x over previous
//
#include <hip/hip_runtime.h>
#include <cstdint>
#include <cstddef>

// Problem constants
#define NB 512
#define NR 1152
#define NC 8
#define NJ 10
#define NO 16
#define NJO 160   // NJ*NO

typedef unsigned int uint32;

// ---- bf16 helpers ----
__device__ __forceinline__ uint32 f2bf(float f) {
    uint32 x = __float_as_uint(f);
    return (x + 0x7fffu + ((x >> 16) & 1u)) >> 16;
}
__device__ __forceinline__ float bflo(uint32 w) { return __uint_as_float(w << 16); }
__device__ __forceinline__ float bfhi(uint32 w) { return __uint_as_float(w & 0xffff0000u); }

// ============================================================================
// Kernel 0: transpose x[b][r][c] -> xT[r][b][c] so uhat can stage x coalesced.
// ============================================================================
__global__ __launch_bounds__(256) void xpose_kernel(const float* __restrict__ x,
                                                    float* __restrict__ xT) {
    const int r0 = blockIdx.x * 16;
    const int b0 = blockIdx.y * 64;
    const int t  = threadIdx.x;
    __shared__ float tile[16][65][8];

    for (int i = t; i < 2048; i += 256) {
        int b = i >> 5, r = (i >> 1) & 15, h = i & 1;
        float4 v = *(const float4*)&x[(size_t)(b0 + b) * (NR * NC) + (size_t)(r0 + r) * NC + h * 4];
        *(float4*)&tile[r][b][h * 4] = v;
    }
    __syncthreads();
    for (int i = t; i < 2048; i += 256) {
        int r = i >> 7, b = (i >> 1) & 63, h = i & 1;
        float4 v = *(const float4*)&tile[r][b][h * 4];
        *(float4*)&xT[(size_t)(r0 + r) * (NB * NC) + (size_t)(b0 + b) * NC + h * 4] = v;
    }
}

// ============================================================================
// Kernel 1: u_hat[b,r,j,o] = sum_c W[r,j,o,c] * xT[r,b,c], bf16 pairs.
// (R4 version — known-good at ~60 us, write-BW-ish bound.)
// ============================================================================
__global__ __launch_bounds__(320) void uhat_kernel(const float* __restrict__ xT,
                                                   const float* __restrict__ W,
                                                   uint32* __restrict__ u) {
    const int r = blockIdx.x;
    const int t = threadIdx.x;

    __shared__ float Ws[NC][NJO];
    __shared__ float xs[NB][NC];

    for (int i = t; i < NJO * NC; i += 320) {
        Ws[i & 7][i >> 3] = W[(size_t)r * (NJO * NC) + i];
    }
    {
        const float4* xsrc = (const float4*)(xT + (size_t)r * (NB * NC));
        float4* xdst = (float4*)&xs[0][0];
        for (int i = t; i < (NB * NC) / 4; i += 320) xdst[i] = xsrc[i];
    }
    __syncthreads();

    const int jo2  = t % 80;
    const int half = t / 80;

    float w0[8], w1[8];
#pragma unroll
    for (int c = 0; c < 8; ++c) {
        w0[c] = Ws[c][2 * jo2];
        w1[c] = Ws[c][2 * jo2 + 1];
    }

    for (int b = half; b < NB; b += 4) {
        const float4* xp = (const float4*)xs[b];
        float4 xa = xp[0], xb = xp[1];
        float a0 = w0[0] * xa.x + w0[1] * xa.y + w0[2] * xa.z + w0[3] * xa.w
                 + w0[4] * xb.x + w0[5] * xb.y + w0[6] * xb.z + w0[7] * xb.w;
        float a1 = w1[0] * xa.x + w1[1] * xa.y + w1[2] * xa.z + w1[3] * xa.w
                 + w1[4] * xb.x + w1[5] * xb.y + w1[6] * xb.z + w1[7] * xb.w;
        uint32 p = f2bf(a0) | (f2bf(a1) << 16);
        u[(size_t)(b * NR + r) * 80 + jo2] = p;
    }
}

// ============================================================================
// Routing pass + fused squash. ONE BLOCK PER b: 576 threads = 9 waves.
// Lane pair split: lane l -> (m = l>>1: r within chunk, h = l&1: j-half).
// Lane handles j in [5h, 5h+5), i.e. u32 pairs [40h, 40h+40) of each row —
// loads are 160 B/lane contiguous => wave reads 10 KB contiguous.
// Wave w covers chunks 4w..4w+3 of 32 r's (9*4*32 = 1152 = all r). Softmax
// denominator is shared across the pair with one shfl_xor(sum,1).
// acc[80] in regs across chunks; ONE 5-stage reduce-scatter per wave over the
// 32 same-h lanes (masks 2..32; 93 shuffles); <=3 LDS atomics per lane;
// 9-wave combine in LDS; in-block squash. NO global atomics, NO s buffers.
// MODE: 0 = uniform c (iter0), write vacc=v0. 1 = middle: vacc += v.
// 2 = final: write out.
// ============================================================================
template <int MODE>
__global__ __launch_bounds__(576, 2) void pass_kernel(const uint32* __restrict__ u,
                                                      float* __restrict__ vacc,
                                                      float* __restrict__ outp) {
    const int b = blockIdx.x;
    const int t = threadIdx.x;
    const int w = t >> 6;       // wave 0..8
    const int l = t & 63;
    const int m = l >> 1;       // 0..31: r within chunk
    const int h = l & 1;        // j-half

    __shared__ float vls[NJO];
    __shared__ float sl[NJO];
    for (int i = t; i < NJO; i += 576) {
        sl[i] = 0.0f;
        if (MODE != 0) vls[i] = vacc[b * NJO + i];
    }
    __syncthreads();

    float acc[80];
#pragma unroll
    for (int i = 0; i < 80; ++i) acc[i] = 0.0f;

    const uint32* ubase = u + (size_t)b * (NR * 80);

#pragma unroll 1
    for (int c4 = 0; c4 < 4; ++c4) {
        const int c = 4 * w + c4;                    // chunk 0..35
        const uint4* up = (const uint4*)(ubase + (size_t)c * 2560 + l * 40);
        uint32 ur[40];
#pragma unroll
        for (int i = 0; i < 10; ++i) {
            uint4 q = up[i];
            ur[4 * i + 0] = q.x; ur[4 * i + 1] = q.y;
            ur[4 * i + 2] = q.z; ur[4 * i + 3] = q.w;
        }

        float cj[5];
        if (MODE == 0) {
#pragma unroll
            for (int j = 0; j < 5; ++j) cj[j] = 0.1f;
        } else {
            float ej[5];
            float ssum = 0.0f;
#pragma unroll
            for (int j = 0; j < 5; ++j) {
                float bj = 0.0f;
#pragma unroll
                for (int q8 = 0; q8 < 8; ++q8) {
                    uint32 uu = ur[8 * j + q8];
                    bj += bflo(uu) * vls[80 * h + 16 * j + 2 * q8]
                        + bfhi(uu) * vls[80 * h + 16 * j + 2 * q8 + 1];
                }
                float e = __expf(bj);   // |bj| <~ 45: safe in fp32
                ej[j] = e;
                ssum += e;
            }
            ssum += __shfl_xor(ssum, 1);   // share denominator across the pair
            float inv = 1.0f / ssum;
#pragma unroll
            for (int j = 0; j < 5; ++j) cj[j] = ej[j] * inv;
        }

#pragma unroll
        for (int j = 0; j < 5; ++j) {
#pragma unroll
            for (int q8 = 0; q8 < 8; ++q8) {
                uint32 uu = ur[8 * j + q8];
                acc[16 * j + 2 * q8]     += cj[j] * bflo(uu);
                acc[16 * j + 2 * q8 + 1] += cj[j] * bfhi(uu);
            }
        }
    }

    // ---- reduce-scatter among the 32 same-h lanes (masks 2,4,8,16,32) ----
    // acc[80] padded to 96; after 5 stages lane owns 3 slots at 3*bitrev5(m).
    float a[48];
    {
        const int bit = (l >> 1) & 1;
#pragma unroll
        for (int i = 0; i < 48; ++i) {
            float lo = acc[i];
            float hi = (i < 32) ? acc[i + 48] : 0.0f;
            float send = bit ? lo : hi;
            float recv = __shfl_xor(send, 2);
            a[i] = (bit ? hi : lo) + recv;
        }
    }
#pragma unroll
    for (int st = 1; st < 5; ++st) {
        const int hw = 48 >> st;                 // 24,12,6,3
        const int bit = (l >> (st + 1)) & 1;
#pragma unroll
        for (int i = 0; i < 24; ++i) {
            if (i < hw) {
                float send = bit ? a[i] : a[i + hw];
                float recv = __shfl_xor(send, 2 << st);
                a[i] = (bit ? a[i + hw] : a[i]) + recv;
            }
        }
    }
    const int base = 3 * (__brev((uint32)m) >> 27);
#pragma unroll
    for (int i = 0; i < 3; ++i) {
        int local = base + i;
        if (local < 80) atomicAdd(&sl[80 * h + local], a[i]);
    }
    __syncthreads();

    // ---- fused squash: thread p < 80 handles jo pair (2p, 2p+1) ----
    if (t < 80) {
        float2 sv = *(const float2*)&sl[2 * t];
        float sq = sv.x * sv.x + sv.y * sv.y;
#pragma unroll
        for (int off = 1; off < 8; off <<= 1) sq += __shfl_xor(sq, off, 8);
        float scale = (sq / (1.0f + sq)) * rsqrtf(sq + 1e-8f);
        float vx = sv.x * scale, vy = sv.y * scale;
        if (MODE == 2) {
            *(float2*)&outp[b * NJO + 2 * t] = make_float2(vx, vy);
        } else if (MODE == 1) {
            float2 va = *(const float2*)&vacc[b * NJO + 2 * t];
            *(float2*)&vacc[b * NJO + 2 * t] = make_float2(va.x + vx, va.y + vy);
        } else {
            *(float2*)&vacc[b * NJO + 2 * t] = make_float2(vx, vy);
        }
    }
}

// ============================================================================
extern "C" void kernel_launch(void* const* d_in, const int* in_sizes, int n_in,
                              void* d_out, int out_size, void* d_ws, size_t ws_size,
                              hipStream_t stream) {
    (void)in_sizes; (void)n_in; (void)out_size; (void)ws_size;

    const float* x = (const float*)d_in[0];  // [B,R,C]
    const float* W = (const float*)d_in[1];  // [R,J,O,C]
    float* out = (float*)d_out;              // [B,J,O,1] fp32

    char* ws = (char*)d_ws;
    const size_t XBYTES = (size_t)NR * NB * NC * 4;   // 18,874,368
    const size_t UBYTES = (size_t)NB * NR * NJO * 2;  // 188,743,680
    float*  xT   = (float*)ws;
    uint32* u    = (uint32*)(ws + XBYTES);
    float*  vacc = (float*)(ws + XBYTES + UBYTES);    // [B,160] fp32 running v-sum

    xpose_kernel<<<dim3(NR / 16, NB / 64), 256, 0, stream>>>(x, xT);
    uhat_kernel<<<NR, 320, 0, stream>>>(xT, W, u);

    // iter 0: c uniform -> s0 -> v0 (vacc = v0)
    pass_kernel<0><<<NB, 576, 0, stream>>>(u, vacc, nullptr);
    // iter 1: b1 = u.v0 -> s1 -> v1 (vacc = v0+v1)
    pass_kernel<1><<<NB, 576, 0, stream>>>(u, vacc, nullptr);
    // iter 2: b2 = u.(v0+v1) -> s2 -> v2 = output
    pass_kernel<2><<<NB, 576, 0, stream>>>(u, vacc, out);
}

// Round 8
// 230.999 us; speedup vs baseline: 3.2136x; 2.1757x over previous
//
#include <hip/hip_runtime.h>
#include <cstdint>
#include <cstddef>

// Problem constants
#define NB 512
#define NR 1152
#define NC 8
#define NJ 10
#define NO 16
#define NJO 160   // NJ*NO

typedef unsigned int uint32;

// ---- bf16 helpers ----
__device__ __forceinline__ uint32 f2bf(float f) {
    uint32 x = __float_as_uint(f);
    return (x + 0x7fffu + ((x >> 16) & 1u)) >> 16;
}
__device__ __forceinline__ float bflo(uint32 w) { return __uint_as_float(w << 16); }
__device__ __forceinline__ float bfhi(uint32 w) { return __uint_as_float(w & 0xffff0000u); }

// ============================================================================
// Kernel 0: transpose x[b][r][c] -> xT[r][b][c] so uhat can stage x coalesced.
// ============================================================================
__global__ __launch_bounds__(256) void xpose_kernel(const float* __restrict__ x,
                                                    float* __restrict__ xT) {
    const int r0 = blockIdx.x * 16;
    const int b0 = blockIdx.y * 64;
    const int t  = threadIdx.x;
    __shared__ float tile[16][65][8];

    for (int i = t; i < 2048; i += 256) {
        int b = i >> 5, r = (i >> 1) & 15, h = i & 1;
        float4 v = *(const float4*)&x[(size_t)(b0 + b) * (NR * NC) + (size_t)(r0 + r) * NC + h * 4];
        *(float4*)&tile[r][b][h * 4] = v;
    }
    __syncthreads();
    for (int i = t; i < 2048; i += 256) {
        int r = i >> 7, b = (i >> 1) & 63, h = i & 1;
        float4 v = *(const float4*)&tile[r][b][h * 4];
        *(float4*)&xT[(size_t)(r0 + r) * (NB * NC) + (size_t)(b0 + b) * NC + h * 4] = v;
    }
}

// ============================================================================
// Kernel 1: u_hat[b,r,j,o] = sum_c W[r,j,o,c] * xT[r,b,c], bf16 pairs.
// (known-good ~60 us, write-BW-ish bound)
// ============================================================================
__global__ __launch_bounds__(320) void uhat_kernel(const float* __restrict__ xT,
                                                   const float* __restrict__ W,
                                                   uint32* __restrict__ u) {
    const int r = blockIdx.x;
    const int t = threadIdx.x;

    __shared__ float Ws[NC][NJO];
    __shared__ float xs[NB][NC];

    for (int i = t; i < NJO * NC; i += 320) {
        Ws[i & 7][i >> 3] = W[(size_t)r * (NJO * NC) + i];
    }
    {
        const float4* xsrc = (const float4*)(xT + (size_t)r * (NB * NC));
        float4* xdst = (float4*)&xs[0][0];
        for (int i = t; i < (NB * NC) / 4; i += 320) xdst[i] = xsrc[i];
    }
    __syncthreads();

    const int jo2  = t % 80;
    const int half = t / 80;

    float w0[8], w1[8];
#pragma unroll
    for (int c = 0; c < 8; ++c) {
        w0[c] = Ws[c][2 * jo2];
        w1[c] = Ws[c][2 * jo2 + 1];
    }

    for (int b = half; b < NB; b += 4) {
        const float4* xp = (const float4*)xs[b];
        float4 xa = xp[0], xb = xp[1];
        float a0 = w0[0] * xa.x + w0[1] * xa.y + w0[2] * xa.z + w0[3] * xa.w
                 + w0[4] * xb.x + w0[5] * xb.y + w0[6] * xb.z + w0[7] * xb.w;
        float a1 = w1[0] * xa.x + w1[1] * xa.y + w1[2] * xa.z + w1[3] * xa.w
                 + w1[4] * xb.x + w1[5] * xb.y + w1[6] * xb.z + w1[7] * xb.w;
        uint32 p = f2bf(a0) | (f2bf(a1) << 16);
        u[(size_t)(b * NR + r) * 80 + jo2] = p;
    }
}

// ============================================================================
// Routing pass + fused squash. ONE BLOCK PER b: 576 threads = 9 waves.
// QUAD split: lane l -> (m = (l>>2)&15: row-in-chunk, qt = l&3: o-quarter).
// Lane covers o in [4qt, 4qt+4) of every j  ->  ur[20], acc[40], cj[10]:
// ~90 VGPRs, NO SPILL at 2 blocks/CU (R7's failure: acc[80]+ur[40] vs the
// 84-reg cap => 195 MB of scratch spill traffic per pass).
// Per chunk (16 rows): lane loads 10 x dwordx2 (quad-contiguous 32B);
// b_ij dot combines o-quarters via shfl_xor(1|2) (DPP); softmax in-lane;
// acc += c*u. After 8 chunks: 4-stage reduce-scatter over the 16 m-lanes
// (masks 4,8,16,32; 45 shuffles), <=3 LDS atomics/lane, in-block squash.
// NO global atomics, NO s buffers, NO memset.
// MODE: 0 = uniform c, vacc = v0. 1 = vacc += v. 2 = write out.
// ============================================================================
template <int MODE>
__global__ __launch_bounds__(576, 2) void pass_kernel(const uint32* __restrict__ u,
                                                      float* __restrict__ vacc,
                                                      float* __restrict__ outp) {
    const int b  = blockIdx.x;
    const int t  = threadIdx.x;
    const int w  = t >> 6;        // wave 0..8
    const int l  = t & 63;
    const int m  = (l >> 2) & 15; // row within chunk
    const int qt = l & 3;         // o-quarter

    __shared__ float vls[NJO];
    __shared__ float sl[NJO];
    for (int i = t; i < NJO; i += 576) {
        sl[i] = 0.0f;
        if (MODE != 0) vls[i] = vacc[b * NJO + i];
    }
    __syncthreads();

    float acc[40];
#pragma unroll
    for (int i = 0; i < 40; ++i) acc[i] = 0.0f;

    const uint32* ubase = u + (size_t)b * (NR * 80);

#pragma unroll 1
    for (int c8 = 0; c8 < 8; ++c8) {
        const int r = (w * 8 + c8) * 16 + m;       // all 1152 rows covered
        const uint32* up = ubase + r * 80 + 2 * qt;

        uint32 ur[20];
#pragma unroll
        for (int j = 0; j < NJ; ++j) {
            uint2 q = *(const uint2*)(up + 8 * j);
            ur[2 * j]     = q.x;
            ur[2 * j + 1] = q.y;
        }

        float cj[NJ];
        if (MODE == 0) {
#pragma unroll
            for (int j = 0; j < NJ; ++j) cj[j] = 0.1f;
        } else {
            float sum = 0.0f;
#pragma unroll
            for (int j = 0; j < NJ; ++j) {
                float4 vv = *(const float4*)&vls[16 * j + 4 * qt];
                float pj = bflo(ur[2 * j]) * vv.x + bfhi(ur[2 * j]) * vv.y
                         + bflo(ur[2 * j + 1]) * vv.z + bfhi(ur[2 * j + 1]) * vv.w;
                pj += __shfl_xor(pj, 1);   // combine o-quarters (DPP)
                pj += __shfl_xor(pj, 2);
                float e = __expf(pj);      // |b_ij| <~ 70 at iter2: safe in fp32
                cj[j] = e;
                sum += e;
            }
            float inv = 1.0f / sum;
#pragma unroll
            for (int j = 0; j < NJ; ++j) cj[j] *= inv;
        }

#pragma unroll
        for (int j = 0; j < NJ; ++j) {
            acc[4 * j + 0] += cj[j] * bflo(ur[2 * j]);
            acc[4 * j + 1] += cj[j] * bfhi(ur[2 * j]);
            acc[4 * j + 2] += cj[j] * bflo(ur[2 * j + 1]);
            acc[4 * j + 3] += cj[j] * bfhi(ur[2 * j + 1]);
        }
    }

    // ---- reduce-scatter among the 16 same-qt lanes (masks 4,8,16,32) ----
    // acc[40] padded to 48; lane ends owning 3 slots at 3*bitrev4(m).
    float a[24];
    {
        const int bit = (l >> 2) & 1;
#pragma unroll
        for (int i = 0; i < 24; ++i) {
            float lo = acc[i];
            float hi = (i + 24 < 40) ? acc[i + 24] : 0.0f;
            float send = bit ? lo : hi;
            float recv = __shfl_xor(send, 4);
            a[i] = (bit ? hi : lo) + recv;
        }
    }
#pragma unroll
    for (int st = 1; st < 4; ++st) {
        const int h = 24 >> st;              // 12,6,3
        const int bit = (l >> (2 + st)) & 1;
#pragma unroll
        for (int i = 0; i < 12; ++i) {
            if (i < h) {
                float send = bit ? a[i] : a[i + h];
                float recv = __shfl_xor(send, 4 << st);
                a[i] = (bit ? a[i + h] : a[i]) + recv;
            }
        }
    }
    const int base = 3 * (__brev((uint32)m) >> 28);
#pragma unroll
    for (int i = 0; i < 3; ++i) {
        int aidx = base + i;
        if (aidx < 40) {
            int j = aidx >> 2, e = aidx & 3;
            atomicAdd(&sl[16 * j + 4 * qt + e], a[i]);
        }
    }
    __syncthreads();

    // ---- fused squash: thread p < 80 handles jo pair (2p, 2p+1) ----
    if (t < 80) {
        float2 sv = *(const float2*)&sl[2 * t];
        float sq = sv.x * sv.x + sv.y * sv.y;
#pragma unroll
        for (int off = 1; off < 8; off <<= 1) sq += __shfl_xor(sq, off, 8);
        float scale = (sq / (1.0f + sq)) * rsqrtf(sq + 1e-8f);
        float vx = sv.x * scale, vy = sv.y * scale;
        if (MODE == 2) {
            *(float2*)&outp[b * NJO + 2 * t] = make_float2(vx, vy);
        } else if (MODE == 1) {
            float2 va = *(const float2*)&vacc[b * NJO + 2 * t];
            *(float2*)&vacc[b * NJO + 2 * t] = make_float2(va.x + vx, va.y + vy);
        } else {
            *(float2*)&vacc[b * NJO + 2 * t] = make_float2(vx, vy);
        }
    }
}

// ============================================================================
extern "C" void kernel_launch(void* const* d_in, const int* in_sizes, int n_in,
                              void* d_out, int out_size, void* d_ws, size_t ws_size,
                              hipStream_t stream) {
    (void)in_sizes; (void)n_in; (void)out_size; (void)ws_size;

    const float* x = (const float*)d_in[0];  // [B,R,C]
    const float* W = (const float*)d_in[1];  // [R,J,O,C]
    float* out = (float*)d_out;              // [B,J,O,1] fp32

    char* ws = (char*)d_ws;
    const size_t XBYTES = (size_t)NR * NB * NC * 4;   // 18,874,368
    const size_t UBYTES = (size_t)NB * NR * NJO * 2;  // 188,743,680
    float*  xT   = (float*)ws;
    uint32* u    = (uint32*)(ws + XBYTES);
    float*  vacc = (float*)(ws + XBYTES + UBYTES);    // [B,160] fp32 running v-sum

    xpose_kernel<<<dim3(NR / 16, NB / 64), 256, 0, stream>>>(x, xT);
    uhat_kernel<<<NR, 320, 0, stream>>>(xT, W, u);

    // iter 0: c uniform -> v0 (vacc = v0)
    pass_kernel<0><<<NB, 576, 0, stream>>>(u, vacc, nullptr);
    // iter 1: b1 = u.v0 -> v1 (vacc = v0+v1)
    pass_kernel<1><<<NB, 576, 0, stream>>>(u, vacc, nullptr);
    // iter 2: b2 = u.(v0+v1) -> v2 = output
    pass_kernel<2><<<NB, 576, 0, stream>>>(u, vacc, out);
}

// Round 9
// 219.429 us; speedup vs baseline: 3.3831x; 1.0527x over previous
//
#include <hip/hip_runtime.h>
#include <hip/hip_fp16.h>
#include <cstdint>
#include <cstddef>

// Problem constants
#define NB 512
#define NR 1152
#define NC 8
#define NJ 10
#define NO 16
#define NJO 160   // NJ*NO

typedef unsigned int uint32;

union H2U { __half2 h; uint32 u; };

__device__ __forceinline__ uint32 packf16(float a0, float a1) {
    H2U p;
    p.h = __halves2half2(__float2half_rn(a0), __float2half_rn(a1));
    return p.u;
}
__device__ __forceinline__ float2 unpackf16(uint32 w) {
    H2U p; p.u = w;
    return __half22float2(p.h);
}

// ============================================================================
// Kernel 0: transpose x[b][r][c] -> xT[r][b][c] so uhat can stage x coalesced.
// ============================================================================
__global__ __launch_bounds__(256) void xpose_kernel(const float* __restrict__ x,
                                                    float* __restrict__ xT) {
    const int r0 = blockIdx.x * 16;
    const int b0 = blockIdx.y * 64;
    const int t  = threadIdx.x;
    __shared__ float tile[16][65][8];

    for (int i = t; i < 2048; i += 256) {
        int b = i >> 5, r = (i >> 1) & 15, h = i & 1;
        float4 v = *(const float4*)&x[(size_t)(b0 + b) * (NR * NC) + (size_t)(r0 + r) * NC + h * 4];
        *(float4*)&tile[r][b][h * 4] = v;
    }
    __syncthreads();
    for (int i = t; i < 2048; i += 256) {
        int r = i >> 7, b = (i >> 1) & 63, h = i & 1;
        float4 v = *(const float4*)&tile[r][b][h * 4];
        *(float4*)&xT[(size_t)(r0 + r) * (NB * NC) + (size_t)(b0 + b) * NC + h * 4] = v;
    }
}

// ============================================================================
// Kernel 1: u_hat -> f16 pairs in QUAD-BLOCKED row layout.
// Row (b,r) = 80 u32; slot ni = qt*20 + 2*j + d holds f16 pair
// (o = 4qt+2d, 4qt+2d+1) of capsule j. A lane in the routing kernel owning
// o-quarter qt reads u32s [qt*20, qt*20+20) -- contiguous, 5 x dwordx4.
// Ws stride padded to 164 (bank (4c+jo)%32 -> conflict-free staging).
// ============================================================================
__global__ __launch_bounds__(320) void uhat_kernel(const float* __restrict__ xT,
                                                   const float* __restrict__ W,
                                                   uint32* __restrict__ u) {
    const int r = blockIdx.x;
    const int t = threadIdx.x;

    __shared__ float Ws[NC][NJO + 4];   // stride 164: staging conflict-free
    __shared__ float xs[NB][NC];

    for (int i = t; i < NJO * NC; i += 320) {
        Ws[i & 7][i >> 3] = W[(size_t)r * (NJO * NC) + i];
    }
    {
        const float4* xsrc = (const float4*)(xT + (size_t)r * (NB * NC));
        float4* xdst = (float4*)&xs[0][0];
        for (int i = t; i < (NB * NC) / 4; i += 320) xdst[i] = xsrc[i];
    }
    __syncthreads();

    const int ni   = t % 80;   // u32 slot in the permuted row
    const int half = t / 80;
    const int qt  = ni / 20;
    const int rem = ni % 20;
    const int j   = rem >> 1;
    const int d   = rem & 1;
    const int jo0 = 16 * j + 4 * qt + 2 * d;   // o index pair (jo0, jo0+1)

    float w0[8], w1[8];
#pragma unroll
    for (int c = 0; c < 8; ++c) {
        w0[c] = Ws[c][jo0];
        w1[c] = Ws[c][jo0 + 1];
    }

    for (int b = half; b < NB; b += 4) {
        const float4* xp = (const float4*)xs[b];
        float4 xa = xp[0], xb = xp[1];
        float a0 = w0[0] * xa.x + w0[1] * xa.y + w0[2] * xa.z + w0[3] * xa.w
                 + w0[4] * xb.x + w0[5] * xb.y + w0[6] * xb.z + w0[7] * xb.w;
        float a1 = w1[0] * xa.x + w1[1] * xa.y + w1[2] * xa.z + w1[3] * xa.w
                 + w1[4] * xb.x + w1[5] * xb.y + w1[6] * xb.z + w1[7] * xb.w;
        u[(size_t)(b * NR + r) * 80 + ni] = packf16(a0, a1);
    }
}

// ============================================================================
// Merged routing kernel: ONE launch, 3 iterations. Block = one b (576 thr,
// 9 waves, 2 blocks/CU). All state (s, v, vacc) lives in LDS -- no global
// atomics, no memsets, no inter-kernel u refetch gaps.
// Per iteration: QUAD split (m = row-in-chunk, qt = o-quarter); lane loads
// its 20 contiguous u32 per row as 5 dwordx4 (16B/lane sweet spot).
// Softmax: per-j fp32 dot (unpack f16) + quad shfl combine. acc[40] fp32.
// Then 4-stage reduce-scatter over the 16 m-lanes, <=3 LDS atomics/lane,
// in-block squash, update vls/vaccl, next iteration.
// ============================================================================
__global__ __launch_bounds__(576, 2) void routing_kernel(const uint32* __restrict__ u,
                                                         float* __restrict__ outp) {
    const int b  = blockIdx.x;
    const int t  = threadIdx.x;
    const int w  = t >> 6;        // wave 0..8
    const int l  = t & 63;
    const int m  = (l >> 2) & 15; // row within chunk
    const int qt = l & 3;         // o-quarter

    __shared__ float sl[NJO];     // s accumulator
    __shared__ float vls[NJO];    // current v-sum (fp32), read by dot
    __shared__ float vaccl[NJO];  // running v0+v1 (fp32)

    for (int i = t; i < NJO; i += 576) sl[i] = 0.0f;
    __syncthreads();

    const uint32* ubase = u + (size_t)b * (NR * 80) + qt * 20;

#pragma unroll 1
    for (int it = 0; it < 3; ++it) {
        float acc[40];
#pragma unroll
        for (int i = 0; i < 40; ++i) acc[i] = 0.0f;

#pragma unroll 1
        for (int c8 = 0; c8 < 8; ++c8) {
            const int r = (w * 8 + c8) * 16 + m;
            const uint4* up = (const uint4*)(ubase + (size_t)r * 80);
            uint32 ur[20];
#pragma unroll
            for (int i = 0; i < 5; ++i) {
                uint4 q = up[i];
                ur[4 * i + 0] = q.x; ur[4 * i + 1] = q.y;
                ur[4 * i + 2] = q.z; ur[4 * i + 3] = q.w;
            }

            float cj[NJ];
            if (it == 0) {
#pragma unroll
                for (int j = 0; j < NJ; ++j) cj[j] = 0.1f;
            } else {
                float sum = 0.0f;
#pragma unroll
                for (int j = 0; j < NJ; ++j) {
                    float2 ua = unpackf16(ur[2 * j]);
                    float2 ub = unpackf16(ur[2 * j + 1]);
                    float4 vv = *(const float4*)&vls[16 * j + 4 * qt];
                    float pj = ua.x * vv.x + ua.y * vv.y + ub.x * vv.z + ub.y * vv.w;
                    pj += __shfl_xor(pj, 1);   // combine o-quarters (DPP)
                    pj += __shfl_xor(pj, 2);
                    float e = __expf(pj);      // |b_ij| <~ 70: safe in fp32
                    cj[j] = e;
                    sum += e;
                }
                float inv = 1.0f / sum;
#pragma unroll
                for (int j = 0; j < NJ; ++j) cj[j] *= inv;
            }

#pragma unroll
            for (int j = 0; j < NJ; ++j) {
                float2 ua = unpackf16(ur[2 * j]);
                float2 ub = unpackf16(ur[2 * j + 1]);
                acc[4 * j + 0] += cj[j] * ua.x;
                acc[4 * j + 1] += cj[j] * ua.y;
                acc[4 * j + 2] += cj[j] * ub.x;
                acc[4 * j + 3] += cj[j] * ub.y;
            }
        }

        // ---- reduce-scatter among the 16 same-qt lanes (masks 4,8,16,32) ----
        float a[24];
        {
            const int bit = (l >> 2) & 1;
#pragma unroll
            for (int i = 0; i < 24; ++i) {
                float lo = acc[i];
                float hi = (i + 24 < 40) ? acc[i + 24] : 0.0f;
                float send = bit ? lo : hi;
                float recv = __shfl_xor(send, 4);
                a[i] = (bit ? hi : lo) + recv;
            }
        }
#pragma unroll
        for (int st = 1; st < 4; ++st) {
            const int h = 24 >> st;              // 12,6,3
            const int bit = (l >> (2 + st)) & 1;
#pragma unroll
            for (int i = 0; i < 12; ++i) {
                if (i < h) {
                    float send = bit ? a[i] : a[i + h];
                    float recv = __shfl_xor(send, 4 << st);
                    a[i] = (bit ? a[i + h] : a[i]) + recv;
                }
            }
        }
        const int base = 3 * (__brev((uint32)m) >> 28);
#pragma unroll
        for (int i = 0; i < 3; ++i) {
            int aidx = base + i;
            if (aidx < 40) {
                int j = aidx >> 2, e = aidx & 3;
                atomicAdd(&sl[16 * j + 4 * qt + e], a[i]);
            }
        }
        __syncthreads();

        // ---- in-block squash: thread p<80 owns o-pair (2p, 2p+1) ----
        if (t < 80) {
            float2 sv = *(const float2*)&sl[2 * t];
            float sq = sv.x * sv.x + sv.y * sv.y;
#pragma unroll
            for (int off = 1; off < 8; off <<= 1) sq += __shfl_xor(sq, off, 8);
            float scale = (sq / (1.0f + sq)) * rsqrtf(sq + 1e-8f);
            float vx = sv.x * scale, vy = sv.y * scale;
            if (it == 2) {
                *(float2*)&outp[b * NJO + 2 * t] = make_float2(vx, vy);
            } else {
                float2 va;
                if (it == 0) va = make_float2(vx, vy);
                else {
                    va = *(const float2*)&vaccl[2 * t];
                    va.x += vx; va.y += vy;
                }
                *(float2*)&vaccl[2 * t] = va;
                *(float2*)&vls[2 * t]   = va;
            }
        }
        __syncthreads();
        if (it < 2) {
            for (int i = t; i < NJO; i += 576) sl[i] = 0.0f;
            __syncthreads();
        }
    }
}

// ============================================================================
extern "C" void kernel_launch(void* const* d_in, const int* in_sizes, int n_in,
                              void* d_out, int out_size, void* d_ws, size_t ws_size,
                              hipStream_t stream) {
    (void)in_sizes; (void)n_in; (void)out_size; (void)ws_size;

    const float* x = (const float*)d_in[0];  // [B,R,C]
    const float* W = (const float*)d_in[1];  // [R,J,O,C]
    float* out = (float*)d_out;              // [B,J,O,1] fp32

    char* ws = (char*)d_ws;
    const size_t XBYTES = (size_t)NR * NB * NC * 4;   // 18,874,368
    float*  xT = (float*)ws;
    uint32* u  = (uint32*)(ws + XBYTES);              // [B,R,80] f16 pairs

    xpose_kernel<<<dim3(NR / 16, NB / 64), 256, 0, stream>>>(x, xT);
    uhat_kernel<<<NR, 320, 0, stream>>>(xT, W, u);
    routing_kernel<<<NB, 576, 0, stream>>>(u, out);
}